// Round 8
// baseline (455.343 us; speedup 1.0000x reference)
//
#include <hip/hip_runtime.h>
#include <cstdint>
#include <cstddef>

#define TT 4096   // T = H*W
#define CCH 256   // C

typedef __attribute__((ext_vector_type(8))) short short8;
typedef __attribute__((ext_vector_type(4))) float f32x4;

__device__ __forceinline__ float bf2f(unsigned int u){
  union { unsigned int i; float f; } v; v.i = u << 16; return v.f;
}
__device__ __forceinline__ unsigned short f2bf(float f){      // RNE
  unsigned int x = __float_as_uint(f);
  x += 0x7fffu + ((x >> 16) & 1u);
  return (unsigned short)(x >> 16);
}
__device__ __forceinline__ unsigned short f2bf_t(float f){    // truncate (p in [0,1])
  return (unsigned short)(__float_as_uint(f) >> 16);
}
// XOR-swizzled element offset for 64-wide LDS rows (16B granule swizzle):
// row*64 + ((granule ^ (row&7))<<3) + sub. Conflict-free for b128/b64
// reads AND writes in all patterns used below; no padding needed.
__device__ __forceinline__ int sw(int row, int col){
  return (row << 6) + ((((col >> 3) ^ (row & 7)) << 3)) + (col & 7);
}

// ---------------- Kernel 1: fused weight-convert + GroupNorm stats ----------
__global__ __launch_bounds__(256)
void wconv_gn(const float* __restrict__ qkv_w, const float* __restrict__ proj_w,
              const float* __restrict__ x,
              unsigned short* __restrict__ wq_bf, unsigned short* __restrict__ wp_bf,
              float* __restrict__ stats){
  int bid = blockIdx.x, tid = threadIdx.x;
  if (bid < 256){
    const float* src = (bid < 192) ? qkv_w : proj_w;
    unsigned short* dst = (bid < 192) ? wq_bf : wp_bf;
    int i = (bid < 192 ? bid : bid - 192) * 256 + tid;
    float4 u = *(const float4*)(src + (size_t)i * 4);
    ushort4 r; r.x = f2bf(u.x); r.y = f2bf(u.y); r.z = f2bf(u.z); r.w = f2bf(u.w);
    *(ushort4*)(dst + (size_t)i * 4) = r;
    return;
  }
  int sg = bid - 256;                         // b*32+g
  const float4* p = (const float4*)(x + (size_t)sg * 32768);
  float s = 0.f, sq = 0.f;
  #pragma unroll
  for (int it = 0; it < 32; ++it){
    float4 u = p[it * 256 + tid];
    s  += u.x + u.y + u.z + u.w;
    sq += u.x*u.x + u.y*u.y + u.z*u.z + u.w*u.w;
  }
  #pragma unroll
  for (int off = 32; off >= 1; off >>= 1){
    s  += __shfl_down(s, off);
    sq += __shfl_down(sq, off);
  }
  __shared__ float ls[4], lq[4];
  int w_ = tid >> 6, lane = tid & 63;
  if (lane == 0){ ls[w_] = s; lq[w_] = sq; }
  __syncthreads();
  if (tid == 0){
    float S = ls[0]+ls[1]+ls[2]+ls[3];
    float Q = lq[0]+lq[1]+lq[2]+lq[3];
    float mean = S * (1.f/32768.f);
    float var  = Q * (1.f/32768.f) - mean*mean;
    stats[2*sg]   = mean;
    stats[2*sg+1] = rsqrtf(var + 1e-5f);
  }
}

// ---------------- Kernel 2: GN apply + transpose -> xnT bf16 [b][t][256] ----
__global__ __launch_bounds__(256)
void gn_apply_t(const float* __restrict__ x, const float* __restrict__ gw,
                const float* __restrict__ gb, const float* __restrict__ stats,
                unsigned short* __restrict__ xnT){
  __shared__ unsigned short t_lds[64][72];
  int tid = threadIdx.x;
  int t0 = blockIdx.x << 6, c0 = blockIdx.y << 6, b = blockIdx.z;
  int t4 = (tid & 15) << 2, cr = tid >> 4;
  #pragma unroll
  for (int pass = 0; pass < 4; ++pass){
    int cl = (pass << 4) + cr;
    int c = c0 + cl;
    int sg = (b << 5) | (c >> 3);
    float mean = stats[2*sg], rstd = stats[2*sg+1];
    float sc = gw[c] * rstd;
    float sh = gb[c] - mean * sc;
    float4 u = *(const float4*)(x + ((size_t)(b*CCH + c))*TT + t0 + t4);
    t_lds[t4+0][cl] = f2bf(u.x*sc + sh);
    t_lds[t4+1][cl] = f2bf(u.y*sc + sh);
    t_lds[t4+2][cl] = f2bf(u.z*sc + sh);
    t_lds[t4+3][cl] = f2bf(u.w*sc + sh);
  }
  __syncthreads();
  #pragma unroll
  for (int pass = 0; pass < 2; ++pass){
    int chunk = (pass << 8) + tid;
    int row = chunk >> 3, c8 = (chunk & 7) << 3;
    *(uint4*)(xnT + ((size_t)b*TT + t0 + row)*256 + c0 + c8) = *(const uint4*)&t_lds[row][c8];
  }
}

// ---------------- Kernel 3: QKV GEMM (bf16 MFMA), swizzled LDS --------------
__global__ __launch_bounds__(256)
void qkv_mfma(const unsigned short* __restrict__ wb, const float* __restrict__ bias,
              const unsigned short* __restrict__ xnT,
              unsigned short* __restrict__ qT, unsigned short* __restrict__ kT,
              unsigned short* __restrict__ vO){
  __shared__ unsigned short x_lds[4096];
  int tid = threadIdx.x;
  int w = tid >> 6, lane = tid & 63, quad = lane >> 4, l15 = lane & 15;
  int t0 = blockIdx.x << 6, o0 = blockIdx.y << 6, b = blockIdx.z;
  const unsigned short* xb = xnT + (size_t)b * TT * 256;
  const unsigned short* wrow = wb + (size_t)(o0 + (w << 4) + l15) * 256;
  f32x4 acc[4];
  #pragma unroll
  for (int nt = 0; nt < 4; ++nt) acc[nt] = (f32x4){0.f,0.f,0.f,0.f};
  for (int ks = 0; ks < 4; ++ks){
    int k0 = ks << 6;
    __syncthreads();
    #pragma unroll
    for (int pass = 0; pass < 2; ++pass){
      int chunk = (pass << 8) + tid;
      int row = chunk >> 3, c8 = (chunk & 7) << 3;
      *(uint4*)&x_lds[sw(row, c8)] = *(const uint4*)(xb + (size_t)(t0 + row)*256 + k0 + c8);
    }
    __syncthreads();
    short8 wa0 = *(const short8*)(wrow + k0 + (quad << 3));
    short8 wa1 = *(const short8*)(wrow + k0 + 32 + (quad << 3));
    #pragma unroll
    for (int nt = 0; nt < 4; ++nt){
      short8 xb0 = *(const short8*)&x_lds[sw((nt << 4) + l15, quad << 3)];
      short8 xb1 = *(const short8*)&x_lds[sw((nt << 4) + l15, 32 + (quad << 3))];
      acc[nt] = __builtin_amdgcn_mfma_f32_16x16x32_bf16(wa0, xb0, acc[nt], 0, 0, 0);
      acc[nt] = __builtin_amdgcn_mfma_f32_16x16x32_bf16(wa1, xb1, acc[nt], 0, 0, 0);
    }
  }
  int sec = blockIdx.y >> 2, h = blockIdx.y & 3, bh = (b << 2) | h;
  float bs[4];
  #pragma unroll
  for (int r = 0; r < 4; ++r) bs[r] = bias[o0 + (w << 4) + (quad << 2) + r];
  __syncthreads();
  if (sec < 2){
    float qsc = (sec == 0) ? 0.125f * 1.44269504f : 1.0f;
    #pragma unroll
    for (int nt = 0; nt < 4; ++nt){
      ushort4 pk;
      pk.x = f2bf((acc[nt][0] + bs[0]) * qsc);
      pk.y = f2bf((acc[nt][1] + bs[1]) * qsc);
      pk.z = f2bf((acc[nt][2] + bs[2]) * qsc);
      pk.w = f2bf((acc[nt][3] + bs[3]) * qsc);
      *(ushort4*)&x_lds[sw((nt << 4) + l15, (w << 4) + (quad << 2))] = pk;
    }
    __syncthreads();
    unsigned short* dst = (sec == 0) ? qT : kT;
    #pragma unroll
    for (int pass = 0; pass < 2; ++pass){
      int chunk = (pass << 8) + tid;
      int row = chunk >> 3, c8 = (chunk & 7) << 3;
      *(uint4*)(dst + ((size_t)bh*TT + t0 + row)*64 + c8) = *(const uint4*)&x_lds[sw(row, c8)];
    }
  } else {
    #pragma unroll
    for (int nt = 0; nt < 4; ++nt)
      #pragma unroll
      for (int r = 0; r < 4; ++r)
        x_lds[sw((w << 4) + (quad << 2) + r, (nt << 4) + l15)] = f2bf(acc[nt][r] + bs[r]);
    __syncthreads();
    #pragma unroll
    for (int pass = 0; pass < 2; ++pass){
      int chunk = (pass << 8) + tid;
      int row = chunk >> 3, c8 = (chunk & 7) << 3;
      *(uint4*)(vO + ((size_t)bh*64 + row)*TT + t0 + c8) = *(const uint4*)&x_lds[sw(row, c8)];
    }
  }
}

// ---------------- Kernel 4: flash attention, 2 q-tiles/wave + swizzle -------
// 1024 blocks x 128 threads (2 waves), 64 q/block, 32 q/wave (2 tiles).
// K,V A-fragments shared across both q-tiles (S^T = K·Q^T, O^T = V·P^T).
// XOR-swizzled LDS (no padding) -> conflict-free reads AND writes.
__global__ __launch_bounds__(128, 2)
void attn6(const unsigned short* __restrict__ qT, const unsigned short* __restrict__ kT,
           const unsigned short* __restrict__ vO, unsigned short* __restrict__ aT){
  __shared__ __align__(16) unsigned short k_lds[4096];   // [s][c] swizzled
  __shared__ __align__(16) unsigned short v_lds[4096];   // [c][s] swizzled
  __shared__ __align__(16) unsigned short p_lds[4096];   // [t][s]; reused as O[t][c]
  int tid = threadIdx.x;
  int w = tid >> 6, lane = tid & 63, quad = lane >> 4, l15 = lane & 15;
  int bh = blockIdx.x & 15, qt6 = blockIdx.x >> 4;       // XCD swizzle
  int t0 = qt6 << 6;
  const unsigned short* qg = qT + (size_t)bh * TT * 64;
  const unsigned short* kg = kT + (size_t)bh * TT * 64;
  const unsigned short* vg = vO + (size_t)bh * 64 * TT;
  int tw = t0 + (w << 5);

  short8 qf[2][2];
  #pragma unroll
  for (int qt = 0; qt < 2; ++qt)
    #pragma unroll
    for (int hh = 0; hh < 2; ++hh)
      qf[qt][hh] = *(const short8*)(qg + (size_t)(tw + (qt << 4) + l15)*64 + (hh << 5) + (quad << 3));

  // staging: thread covers rows srow+{0,16,32,48}, 16B granule sg
  int srow = tid >> 3, sg8 = (tid & 7) << 3;
  int soff[4];
  #pragma unroll
  for (int i = 0; i < 4; ++i) soff[i] = sw(srow + (i << 4), sg8);

  f32x4 o_acc[2][4];
  #pragma unroll
  for (int qt = 0; qt < 2; ++qt)
    #pragma unroll
    for (int ct = 0; ct < 4; ++ct) o_acc[qt][ct] = (f32x4){0.f,0.f,0.f,0.f};
  float m_[2] = {-1e30f, -1e30f}, l_[2] = {0.f, 0.f};

  uint4 kr[4], vr[4];
  #pragma unroll
  for (int i = 0; i < 4; ++i){
    kr[i] = *(const uint4*)(kg + (size_t)(srow + (i << 4))*64 + sg8);
    vr[i] = *(const uint4*)(vg + (size_t)(srow + (i << 4))*TT + sg8);
  }

  for (int st = 0; st < 64; ++st){
    __syncthreads();
    #pragma unroll
    for (int i = 0; i < 4; ++i){
      *(uint4*)&k_lds[soff[i]] = kr[i];
      *(uint4*)&v_lds[soff[i]] = vr[i];
    }
    if (st < 63){
      int sn = (st + 1) << 6;
      #pragma unroll
      for (int i = 0; i < 4; ++i){
        kr[i] = *(const uint4*)(kg + (size_t)(sn + srow + (i << 4))*64 + sg8);
        vr[i] = *(const uint4*)(vg + (size_t)(srow + (i << 4))*TT + sn + sg8);
      }
    }
    __syncthreads();
    // S^T: rows s = mt*16+quad*4+r, cols t (2 q-tiles); K fragments shared
    f32x4 sv[4][2];
    #pragma unroll
    for (int mt = 0; mt < 4; ++mt){
      short8 ka0 = *(const short8*)&k_lds[sw((mt << 4) + l15, quad << 3)];
      short8 ka1 = *(const short8*)&k_lds[sw((mt << 4) + l15, 32 + (quad << 3))];
      #pragma unroll
      for (int qt = 0; qt < 2; ++qt){
        f32x4 z = (f32x4){0.f,0.f,0.f,0.f};
        z = __builtin_amdgcn_mfma_f32_16x16x32_bf16(ka0, qf[qt][0], z, 0, 0, 0);
        z = __builtin_amdgcn_mfma_f32_16x16x32_bf16(ka1, qf[qt][1], z, 0, 0, 0);
        sv[mt][qt] = z;
      }
    }
    // online softmax per q-tile
    float alpha[2];
    #pragma unroll
    for (int qt = 0; qt < 2; ++qt){
      float rm = -1e30f;
      #pragma unroll
      for (int mt = 0; mt < 4; ++mt)
        #pragma unroll
        for (int r = 0; r < 4; ++r) rm = fmaxf(rm, sv[mt][qt][r]);
      rm = fmaxf(rm, __shfl_xor(rm, 16));
      rm = fmaxf(rm, __shfl_xor(rm, 32));
      float mnew = fmaxf(m_[qt], rm);
      alpha[qt] = exp2f(m_[qt] - mnew);
      float rs = 0.f;
      int prow = (w << 5) + (qt << 4) + l15;
      #pragma unroll
      for (int mt = 0; mt < 4; ++mt){
        float p0 = exp2f(sv[mt][qt][0] - mnew);
        float p1 = exp2f(sv[mt][qt][1] - mnew);
        float p2 = exp2f(sv[mt][qt][2] - mnew);
        float p3 = exp2f(sv[mt][qt][3] - mnew);
        rs += (p0 + p1) + (p2 + p3);
        ushort4 pk; pk.x = f2bf_t(p0); pk.y = f2bf_t(p1); pk.z = f2bf_t(p2); pk.w = f2bf_t(p3);
        *(ushort4*)&p_lds[sw(prow, (mt << 4) + (quad << 2))] = pk;
      }
      rs += __shfl_xor(rs, 16);
      rs += __shfl_xor(rs, 32);
      l_[qt] = l_[qt]*alpha[qt] + rs;
      m_[qt] = mnew;
      #pragma unroll
      for (int ct = 0; ct < 4; ++ct)
        #pragma unroll
        for (int r = 0; r < 4; ++r) o_acc[qt][ct][r] *= alpha[qt];
    }
    // PV: O^T = V·P^T ; V fragments shared across q-tiles
    short8 pb[2][2];
    #pragma unroll
    for (int qt = 0; qt < 2; ++qt){
      int prow = (w << 5) + (qt << 4) + l15;
      pb[qt][0] = *(const short8*)&p_lds[sw(prow, quad << 3)];
      pb[qt][1] = *(const short8*)&p_lds[sw(prow, 32 + (quad << 3))];
    }
    #pragma unroll
    for (int ct = 0; ct < 4; ++ct){
      short8 va0 = *(const short8*)&v_lds[sw((ct << 4) + l15, quad << 3)];
      short8 va1 = *(const short8*)&v_lds[sw((ct << 4) + l15, 32 + (quad << 3))];
      #pragma unroll
      for (int qt = 0; qt < 2; ++qt){
        o_acc[qt][ct] = __builtin_amdgcn_mfma_f32_16x16x32_bf16(va0, pb[qt][0], o_acc[qt][ct], 0, 0, 0);
        o_acc[qt][ct] = __builtin_amdgcn_mfma_f32_16x16x32_bf16(va1, pb[qt][1], o_acc[qt][ct], 0, 0, 0);
      }
    }
  }
  // epilogue: normalize in-lane, O^T -> p_lds[t][c] (b64), store aT
  __syncthreads();
  #pragma unroll
  for (int qt = 0; qt < 2; ++qt){
    float ir = 1.f / l_[qt];
    int prow = (w << 5) + (qt << 4) + l15;
    #pragma unroll
    for (int ct = 0; ct < 4; ++ct){
      ushort4 ok;
      ok.x = f2bf(o_acc[qt][ct][0] * ir);
      ok.y = f2bf(o_acc[qt][ct][1] * ir);
      ok.z = f2bf(o_acc[qt][ct][2] * ir);
      ok.w = f2bf(o_acc[qt][ct][3] * ir);
      *(ushort4*)&p_lds[sw(prow, (ct << 4) + (quad << 2))] = ok;
    }
  }
  __syncthreads();
  size_t abase = ((size_t)(bh >> 2)*TT + t0)*256 + (size_t)(bh & 3)*64;
  #pragma unroll
  for (int pass = 0; pass < 4; ++pass){
    int chunk = (pass << 7) + tid;
    int row = chunk >> 3, c8 = (chunk & 7) << 3;
    *(uint4*)(aT + abase + (size_t)row*256 + c8) = *(const uint4*)&p_lds[sw(row, c8)];
  }
}

// ---------------- Kernel 5: proj GEMM (bf16 MFMA) + bias + residual ---------
__global__ __launch_bounds__(256)
void proj_mfma(const unsigned short* __restrict__ wb, const float* __restrict__ bias,
               const unsigned short* __restrict__ aT, const float* __restrict__ x,
               float* __restrict__ out){
  __shared__ unsigned short x_lds[4096];
  int tid = threadIdx.x;
  int w = tid >> 6, lane = tid & 63, quad = lane >> 4, l15 = lane & 15;
  int t0 = blockIdx.x << 6, o0 = blockIdx.y << 6, b = blockIdx.z;
  const unsigned short* xb = aT + (size_t)b * TT * 256;
  const unsigned short* wrow = wb + (size_t)(o0 + (w << 4) + l15) * 256;
  f32x4 acc[4];
  #pragma unroll
  for (int nt = 0; nt < 4; ++nt) acc[nt] = (f32x4){0.f,0.f,0.f,0.f};
  for (int ks = 0; ks < 4; ++ks){
    int k0 = ks << 6;
    __syncthreads();
    #pragma unroll
    for (int pass = 0; pass < 2; ++pass){
      int chunk = (pass << 8) + tid;
      int row = chunk >> 3, c8 = (chunk & 7) << 3;
      *(uint4*)&x_lds[sw(row, c8)] = *(const uint4*)(xb + (size_t)(t0 + row)*256 + k0 + c8);
    }
    __syncthreads();
    short8 wa0 = *(const short8*)(wrow + k0 + (quad << 3));
    short8 wa1 = *(const short8*)(wrow + k0 + 32 + (quad << 3));
    #pragma unroll
    for (int nt = 0; nt < 4; ++nt){
      short8 xb0 = *(const short8*)&x_lds[sw((nt << 4) + l15, quad << 3)];
      short8 xb1 = *(const short8*)&x_lds[sw((nt << 4) + l15, 32 + (quad << 3))];
      acc[nt] = __builtin_amdgcn_mfma_f32_16x16x32_bf16(wa0, xb0, acc[nt], 0, 0, 0);
      acc[nt] = __builtin_amdgcn_mfma_f32_16x16x32_bf16(wa1, xb1, acc[nt], 0, 0, 0);
    }
  }
  #pragma unroll
  for (int r = 0; r < 4; ++r){
    int o = o0 + (w << 4) + (quad << 2) + r;
    float bsv = bias[o];
    #pragma unroll
    for (int nt = 0; nt < 4; ++nt){
      size_t idx = ((size_t)(b*CCH + o))*TT + t0 + (nt << 4) + l15;
      out[idx] = acc[nt][r] + bsv + x[idx];
    }
  }
}

extern "C" void kernel_launch(void* const* d_in, const int* in_sizes, int n_in,
                              void* d_out, int out_size, void* d_ws, size_t ws_size,
                              hipStream_t stream){
  const float* x      = (const float*)d_in[0];
  const float* gn_w   = (const float*)d_in[1];
  const float* gn_b   = (const float*)d_in[2];
  const float* qkv_w  = (const float*)d_in[3];
  const float* qkv_b  = (const float*)d_in[4];
  const float* proj_w = (const float*)d_in[5];
  const float* proj_b = (const float*)d_in[6];
  float* out = (float*)d_out;

  float* stats = (float*)d_ws;
  unsigned short* wq_bf = (unsigned short*)(stats + 1024);
  unsigned short* wp_bf = wq_bf + (size_t)768*256;
  unsigned short* xnT   = wp_bf + (size_t)256*256;
  unsigned short* qT    = xnT + (size_t)4*TT*256;
  unsigned short* kT    = qT  + (size_t)16*TT*64;
  unsigned short* vO    = kT  + (size_t)16*TT*64;
  unsigned short* aT    = vO  + (size_t)16*64*TT;

  wconv_gn<<<384, 256, 0, stream>>>(qkv_w, proj_w, x, wq_bf, wp_bf, stats);
  gn_apply_t<<<dim3(64, 4, 4), 256, 0, stream>>>(x, gn_w, gn_b, stats, xnT);
  qkv_mfma<<<dim3(64, 12, 4), 256, 0, stream>>>(wq_bf, qkv_b, xnT, qT, kT, vO);
  attn6<<<1024, 128, 0, stream>>>(qT, kT, vO, aT);
  proj_mfma<<<dim3(64, 4, 4), 256, 0, stream>>>(wp_bf, proj_b, aT, x, out);
}

// Round 9
// 246.676 us; speedup vs baseline: 1.8459x; 1.8459x over previous
//
#include <hip/hip_runtime.h>
#include <cstdint>
#include <cstddef>

#define TT 4096   // T = H*W
#define CCH 256   // C

typedef __attribute__((ext_vector_type(8))) short short8;
typedef __attribute__((ext_vector_type(4))) float f32x4;

__device__ __forceinline__ float bf2f(unsigned int u){
  union { unsigned int i; float f; } v; v.i = u << 16; return v.f;
}
__device__ __forceinline__ unsigned short f2bf(float f){      // RNE
  unsigned int x = __float_as_uint(f);
  x += 0x7fffu + ((x >> 16) & 1u);
  return (unsigned short)(x >> 16);
}
__device__ __forceinline__ unsigned short f2bf_t(float f){    // truncate (p in [0,1])
  return (unsigned short)(__float_as_uint(f) >> 16);
}
// XOR-swizzled element offset for 64-wide LDS rows (16B granule swizzle).
__device__ __forceinline__ int sw(int row, int col){
  return (row << 6) + ((((col >> 3) ^ (row & 7)) << 3)) + (col & 7);
}

// ---------------- Kernel 1: fused weight-convert + GroupNorm stats ----------
__global__ __launch_bounds__(256)
void wconv_gn(const float* __restrict__ qkv_w, const float* __restrict__ proj_w,
              const float* __restrict__ x,
              unsigned short* __restrict__ wq_bf, unsigned short* __restrict__ wp_bf,
              float* __restrict__ stats){
  int bid = blockIdx.x, tid = threadIdx.x;
  if (bid < 256){
    const float* src = (bid < 192) ? qkv_w : proj_w;
    unsigned short* dst = (bid < 192) ? wq_bf : wp_bf;
    int i = (bid < 192 ? bid : bid - 192) * 256 + tid;
    float4 u = *(const float4*)(src + (size_t)i * 4);
    ushort4 r; r.x = f2bf(u.x); r.y = f2bf(u.y); r.z = f2bf(u.z); r.w = f2bf(u.w);
    *(ushort4*)(dst + (size_t)i * 4) = r;
    return;
  }
  int sg = bid - 256;                         // b*32+g
  const float4* p = (const float4*)(x + (size_t)sg * 32768);
  float s = 0.f, sq = 0.f;
  #pragma unroll
  for (int it = 0; it < 32; ++it){
    float4 u = p[it * 256 + tid];
    s  += u.x + u.y + u.z + u.w;
    sq += u.x*u.x + u.y*u.y + u.z*u.z + u.w*u.w;
  }
  #pragma unroll
  for (int off = 32; off >= 1; off >>= 1){
    s  += __shfl_down(s, off);
    sq += __shfl_down(sq, off);
  }
  __shared__ float ls[4], lq[4];
  int w_ = tid >> 6, lane = tid & 63;
  if (lane == 0){ ls[w_] = s; lq[w_] = sq; }
  __syncthreads();
  if (tid == 0){
    float S = ls[0]+ls[1]+ls[2]+ls[3];
    float Q = lq[0]+lq[1]+lq[2]+lq[3];
    float mean = S * (1.f/32768.f);
    float var  = Q * (1.f/32768.f) - mean*mean;
    stats[2*sg]   = mean;
    stats[2*sg+1] = rsqrtf(var + 1e-5f);
  }
}

// ---------------- Kernel 2: GN apply + transpose -> xnT bf16 [b][t][256] ----
__global__ __launch_bounds__(256)
void gn_apply_t(const float* __restrict__ x, const float* __restrict__ gw,
                const float* __restrict__ gb, const float* __restrict__ stats,
                unsigned short* __restrict__ xnT){
  __shared__ unsigned short t_lds[64][72];
  int tid = threadIdx.x;
  int t0 = blockIdx.x << 6, c0 = blockIdx.y << 6, b = blockIdx.z;
  int t4 = (tid & 15) << 2, cr = tid >> 4;
  #pragma unroll
  for (int pass = 0; pass < 4; ++pass){
    int cl = (pass << 4) + cr;
    int c = c0 + cl;
    int sg = (b << 5) | (c >> 3);
    float mean = stats[2*sg], rstd = stats[2*sg+1];
    float sc = gw[c] * rstd;
    float sh = gb[c] - mean * sc;
    float4 u = *(const float4*)(x + ((size_t)(b*CCH + c))*TT + t0 + t4);
    t_lds[t4+0][cl] = f2bf(u.x*sc + sh);
    t_lds[t4+1][cl] = f2bf(u.y*sc + sh);
    t_lds[t4+2][cl] = f2bf(u.z*sc + sh);
    t_lds[t4+3][cl] = f2bf(u.w*sc + sh);
  }
  __syncthreads();
  #pragma unroll
  for (int pass = 0; pass < 2; ++pass){
    int chunk = (pass << 8) + tid;
    int row = chunk >> 3, c8 = (chunk & 7) << 3;
    *(uint4*)(xnT + ((size_t)b*TT + t0 + row)*256 + c0 + c8) = *(const uint4*)&t_lds[row][c8];
  }
}

// ---------------- Kernel 3: QKV GEMM (bf16 MFMA), swizzled LDS --------------
__global__ __launch_bounds__(256)
void qkv_mfma(const unsigned short* __restrict__ wb, const float* __restrict__ bias,
              const unsigned short* __restrict__ xnT,
              unsigned short* __restrict__ qT, unsigned short* __restrict__ kT,
              unsigned short* __restrict__ vO){
  __shared__ unsigned short x_lds[4096];
  int tid = threadIdx.x;
  int w = tid >> 6, lane = tid & 63, quad = lane >> 4, l15 = lane & 15;
  int t0 = blockIdx.x << 6, o0 = blockIdx.y << 6, b = blockIdx.z;
  const unsigned short* xb = xnT + (size_t)b * TT * 256;
  const unsigned short* wrow = wb + (size_t)(o0 + (w << 4) + l15) * 256;
  f32x4 acc[4];
  #pragma unroll
  for (int nt = 0; nt < 4; ++nt) acc[nt] = (f32x4){0.f,0.f,0.f,0.f};
  for (int ks = 0; ks < 4; ++ks){
    int k0 = ks << 6;
    __syncthreads();
    #pragma unroll
    for (int pass = 0; pass < 2; ++pass){
      int chunk = (pass << 8) + tid;
      int row = chunk >> 3, c8 = (chunk & 7) << 3;
      *(uint4*)&x_lds[sw(row, c8)] = *(const uint4*)(xb + (size_t)(t0 + row)*256 + k0 + c8);
    }
    __syncthreads();
    short8 wa0 = *(const short8*)(wrow + k0 + (quad << 3));
    short8 wa1 = *(const short8*)(wrow + k0 + 32 + (quad << 3));
    #pragma unroll
    for (int nt = 0; nt < 4; ++nt){
      short8 xb0 = *(const short8*)&x_lds[sw((nt << 4) + l15, quad << 3)];
      short8 xb1 = *(const short8*)&x_lds[sw((nt << 4) + l15, 32 + (quad << 3))];
      acc[nt] = __builtin_amdgcn_mfma_f32_16x16x32_bf16(wa0, xb0, acc[nt], 0, 0, 0);
      acc[nt] = __builtin_amdgcn_mfma_f32_16x16x32_bf16(wa1, xb1, acc[nt], 0, 0, 0);
    }
  }
  int sec = blockIdx.y >> 2, h = blockIdx.y & 3, bh = (b << 2) | h;
  float bs[4];
  #pragma unroll
  for (int r = 0; r < 4; ++r) bs[r] = bias[o0 + (w << 4) + (quad << 2) + r];
  __syncthreads();
  if (sec < 2){
    float qsc = (sec == 0) ? 0.125f * 1.44269504f : 1.0f;
    #pragma unroll
    for (int nt = 0; nt < 4; ++nt){
      ushort4 pk;
      pk.x = f2bf((acc[nt][0] + bs[0]) * qsc);
      pk.y = f2bf((acc[nt][1] + bs[1]) * qsc);
      pk.z = f2bf((acc[nt][2] + bs[2]) * qsc);
      pk.w = f2bf((acc[nt][3] + bs[3]) * qsc);
      *(ushort4*)&x_lds[sw((nt << 4) + l15, (w << 4) + (quad << 2))] = pk;
    }
    __syncthreads();
    unsigned short* dst = (sec == 0) ? qT : kT;
    #pragma unroll
    for (int pass = 0; pass < 2; ++pass){
      int chunk = (pass << 8) + tid;
      int row = chunk >> 3, c8 = (chunk & 7) << 3;
      *(uint4*)(dst + ((size_t)bh*TT + t0 + row)*64 + c8) = *(const uint4*)&x_lds[sw(row, c8)];
    }
  } else {
    #pragma unroll
    for (int nt = 0; nt < 4; ++nt)
      #pragma unroll
      for (int r = 0; r < 4; ++r)
        x_lds[sw((w << 4) + (quad << 2) + r, (nt << 4) + l15)] = f2bf(acc[nt][r] + bs[r]);
    __syncthreads();
    #pragma unroll
    for (int pass = 0; pass < 2; ++pass){
      int chunk = (pass << 8) + tid;
      int row = chunk >> 3, c8 = (chunk & 7) << 3;
      *(uint4*)(vO + ((size_t)bh*64 + row)*TT + t0 + c8) = *(const uint4*)&x_lds[sw(row, c8)];
    }
  }
}

// ---------------- Kernel 4: flash attention (R7 structure + XOR swizzle) ----
// block = (bh, 64 q), 256 threads, 4 waves x 16 q. bh = blockIdx&15 (XCD).
// S^T = K·Q^T, O^T = V·P^T (in-lane alpha/1/l). K/V staged in LDS w/ reg
// prefetch; XOR-swizzled LDS -> conflict-free staging writes + frag reads.
__global__ __launch_bounds__(256, 4)
void attn7(const unsigned short* __restrict__ qT, const unsigned short* __restrict__ kT,
           const unsigned short* __restrict__ vO, unsigned short* __restrict__ aT){
  __shared__ __align__(16) unsigned short k_lds[4096];   // [s][c] swizzled
  __shared__ __align__(16) unsigned short v_lds[4096];   // [c][s] swizzled
  __shared__ __align__(16) unsigned short p_lds[4096];   // [t][s]; reused as O[t][c]
  int tid = threadIdx.x;
  int w = tid >> 6, lane = tid & 63, quad = lane >> 4, l15 = lane & 15;
  int bh = blockIdx.x & 15, qt6 = blockIdx.x >> 4;       // XCD swizzle
  int t0 = qt6 << 6;
  const unsigned short* qg = qT + (size_t)bh * TT * 64;
  const unsigned short* kg = kT + (size_t)bh * TT * 64;
  const unsigned short* vg = vO + (size_t)bh * 64 * TT;
  int tw = t0 + (w << 4);

  int row0 = tid >> 3, c80 = (tid & 7) << 3;
  int row1 = row0 + 32;
  int soff0 = sw(row0, c80), soff1 = sw(row1, c80);

  short8 qf[2];
  qf[0] = *(const short8*)(qg + (size_t)(tw + l15)*64 + (quad << 3));
  qf[1] = *(const short8*)(qg + (size_t)(tw + l15)*64 + 32 + (quad << 3));

  f32x4 o_acc[4];                      // O^T tiles: row c=ct*16+quad*4+r, col t=l15
  #pragma unroll
  for (int ct = 0; ct < 4; ++ct) o_acc[ct] = (f32x4){0.f,0.f,0.f,0.f};
  float m_ = -1e30f, l_ = 0.f;

  uint4 kr0 = *(const uint4*)(kg + (size_t)row0*64 + c80);
  uint4 kr1 = *(const uint4*)(kg + (size_t)row1*64 + c80);
  uint4 vr0 = *(const uint4*)(vg + (size_t)row0*TT + c80);
  uint4 vr1 = *(const uint4*)(vg + (size_t)row1*TT + c80);

  for (int st = 0; st < 64; ++st){
    __syncthreads();
    *(uint4*)&k_lds[soff0] = kr0;
    *(uint4*)&k_lds[soff1] = kr1;
    *(uint4*)&v_lds[soff0] = vr0;
    *(uint4*)&v_lds[soff1] = vr1;
    if (st < 63){
      int sn = (st + 1) << 6;
      kr0 = *(const uint4*)(kg + (size_t)(sn + row0)*64 + c80);
      kr1 = *(const uint4*)(kg + (size_t)(sn + row1)*64 + c80);
      vr0 = *(const uint4*)(vg + (size_t)row0*TT + sn + c80);
      vr1 = *(const uint4*)(vg + (size_t)row1*TT + sn + c80);
    }
    __syncthreads();
    // S^T: rows s = mt*16+quad*4+r, col t = l15
    f32x4 sv[4];
    #pragma unroll
    for (int mt = 0; mt < 4; ++mt){
      short8 ka0 = *(const short8*)&k_lds[sw((mt << 4) + l15, quad << 3)];
      short8 ka1 = *(const short8*)&k_lds[sw((mt << 4) + l15, 32 + (quad << 3))];
      f32x4 z = (f32x4){0.f,0.f,0.f,0.f};
      z = __builtin_amdgcn_mfma_f32_16x16x32_bf16(ka0, qf[0], z, 0, 0, 0);
      z = __builtin_amdgcn_mfma_f32_16x16x32_bf16(ka1, qf[1], z, 0, 0, 0);
      sv[mt] = z;
    }
    // online softmax over s (in-lane + 2 cross-quad shfl)
    float rm = -1e30f;
    #pragma unroll
    for (int mt = 0; mt < 4; ++mt)
      #pragma unroll
      for (int r = 0; r < 4; ++r) rm = fmaxf(rm, sv[mt][r]);
    rm = fmaxf(rm, __shfl_xor(rm, 16));
    rm = fmaxf(rm, __shfl_xor(rm, 32));
    float mnew = fmaxf(m_, rm);
    float alpha = exp2f(m_ - mnew);
    float rs = 0.f;
    int prow = (w << 4) + l15;
    #pragma unroll
    for (int mt = 0; mt < 4; ++mt){
      float p0 = exp2f(sv[mt][0] - mnew);
      float p1 = exp2f(sv[mt][1] - mnew);
      float p2 = exp2f(sv[mt][2] - mnew);
      float p3 = exp2f(sv[mt][3] - mnew);
      rs += (p0 + p1) + (p2 + p3);
      ushort4 pk; pk.x = f2bf_t(p0); pk.y = f2bf_t(p1); pk.z = f2bf_t(p2); pk.w = f2bf_t(p3);
      *(ushort4*)&p_lds[sw(prow, (mt << 4) + (quad << 2))] = pk;
    }
    rs += __shfl_xor(rs, 16);
    rs += __shfl_xor(rs, 32);
    l_ = l_*alpha + rs;
    m_ = mnew;
    // rescale O^T in-lane
    #pragma unroll
    for (int ct = 0; ct < 4; ++ct)
      #pragma unroll
      for (int r = 0; r < 4; ++r) o_acc[ct][r] *= alpha;
    // PV: O^T = V·P^T
    short8 pb0 = *(const short8*)&p_lds[sw(prow, quad << 3)];
    short8 pb1 = *(const short8*)&p_lds[sw(prow, 32 + (quad << 3))];
    #pragma unroll
    for (int ct = 0; ct < 4; ++ct){
      short8 va0 = *(const short8*)&v_lds[sw((ct << 4) + l15, quad << 3)];
      short8 va1 = *(const short8*)&v_lds[sw((ct << 4) + l15, 32 + (quad << 3))];
      o_acc[ct] = __builtin_amdgcn_mfma_f32_16x16x32_bf16(va0, pb0, o_acc[ct], 0, 0, 0);
      o_acc[ct] = __builtin_amdgcn_mfma_f32_16x16x32_bf16(va1, pb1, o_acc[ct], 0, 0, 0);
    }
  }
  // epilogue: normalize in-lane, O^T -> p_lds[t][c] (b64), store aT
  __syncthreads();
  float ir = 1.f / l_;
  int prow = (w << 4) + l15;
  #pragma unroll
  for (int ct = 0; ct < 4; ++ct){
    ushort4 ok;
    ok.x = f2bf(o_acc[ct][0] * ir);
    ok.y = f2bf(o_acc[ct][1] * ir);
    ok.z = f2bf(o_acc[ct][2] * ir);
    ok.w = f2bf(o_acc[ct][3] * ir);
    *(ushort4*)&p_lds[sw(prow, (ct << 4) + (quad << 2))] = ok;
  }
  __syncthreads();
  size_t abase = ((size_t)(bh >> 2)*TT + t0)*256 + (size_t)(bh & 3)*64;
  #pragma unroll
  for (int pass = 0; pass < 2; ++pass){
    int chunk = (pass << 8) + tid;
    int row = chunk >> 3, c8 = (chunk & 7) << 3;
    *(uint4*)(aT + abase + (size_t)row*256 + c8) = *(const uint4*)&p_lds[sw(row, c8)];
  }
}

// ---------------- Kernel 5: proj GEMM (bf16 MFMA) + bias + residual ---------
__global__ __launch_bounds__(256)
void proj_mfma(const unsigned short* __restrict__ wb, const float* __restrict__ bias,
               const unsigned short* __restrict__ aT, const float* __restrict__ x,
               float* __restrict__ out){
  __shared__ unsigned short x_lds[4096];
  int tid = threadIdx.x;
  int w = tid >> 6, lane = tid & 63, quad = lane >> 4, l15 = lane & 15;
  int t0 = blockIdx.x << 6, o0 = blockIdx.y << 6, b = blockIdx.z;
  const unsigned short* xb = aT + (size_t)b * TT * 256;
  const unsigned short* wrow = wb + (size_t)(o0 + (w << 4) + l15) * 256;
  f32x4 acc[4];
  #pragma unroll
  for (int nt = 0; nt < 4; ++nt) acc[nt] = (f32x4){0.f,0.f,0.f,0.f};
  for (int ks = 0; ks < 4; ++ks){
    int k0 = ks << 6;
    __syncthreads();
    #pragma unroll
    for (int pass = 0; pass < 2; ++pass){
      int chunk = (pass << 8) + tid;
      int row = chunk >> 3, c8 = (chunk & 7) << 3;
      *(uint4*)&x_lds[sw(row, c8)] = *(const uint4*)(xb + (size_t)(t0 + row)*256 + k0 + c8);
    }
    __syncthreads();
    short8 wa0 = *(const short8*)(wrow + k0 + (quad << 3));
    short8 wa1 = *(const short8*)(wrow + k0 + 32 + (quad << 3));
    #pragma unroll
    for (int nt = 0; nt < 4; ++nt){
      short8 xb0 = *(const short8*)&x_lds[sw((nt << 4) + l15, quad << 3)];
      short8 xb1 = *(const short8*)&x_lds[sw((nt << 4) + l15, 32 + (quad << 3))];
      acc[nt] = __builtin_amdgcn_mfma_f32_16x16x32_bf16(wa0, xb0, acc[nt], 0, 0, 0);
      acc[nt] = __builtin_amdgcn_mfma_f32_16x16x32_bf16(wa1, xb1, acc[nt], 0, 0, 0);
    }
  }
  #pragma unroll
  for (int r = 0; r < 4; ++r){
    int o = o0 + (w << 4) + (quad << 2) + r;
    float bsv = bias[o];
    #pragma unroll
    for (int nt = 0; nt < 4; ++nt){
      size_t idx = ((size_t)(b*CCH + o))*TT + t0 + (nt << 4) + l15;
      out[idx] = acc[nt][r] + bsv + x[idx];
    }
  }
}

extern "C" void kernel_launch(void* const* d_in, const int* in_sizes, int n_in,
                              void* d_out, int out_size, void* d_ws, size_t ws_size,
                              hipStream_t stream){
  const float* x      = (const float*)d_in[0];
  const float* gn_w   = (const float*)d_in[1];
  const float* gn_b   = (const float*)d_in[2];
  const float* qkv_w  = (const float*)d_in[3];
  const float* qkv_b  = (const float*)d_in[4];
  const float* proj_w = (const float*)d_in[5];
  const float* proj_b = (const float*)d_in[6];
  float* out = (float*)d_out;

  float* stats = (float*)d_ws;
  unsigned short* wq_bf = (unsigned short*)(stats + 1024);
  unsigned short* wp_bf = wq_bf + (size_t)768*256;
  unsigned short* xnT   = wp_bf + (size_t)256*256;
  unsigned short* qT    = xnT + (size_t)4*TT*256;
  unsigned short* kT    = qT  + (size_t)16*TT*64;
  unsigned short* vO    = kT  + (size_t)16*TT*64;
  unsigned short* aT    = vO  + (size_t)16*64*TT;

  wconv_gn<<<384, 256, 0, stream>>>(qkv_w, proj_w, x, wq_bf, wp_bf, stats);
  gn_apply_t<<<dim3(64, 4, 4), 256, 0, stream>>>(x, gn_w, gn_b, stats, xnT);
  qkv_mfma<<<dim3(64, 12, 4), 256, 0, stream>>>(wq_bf, qkv_b, xnT, qT, kT, vO);
  attn7<<<1024, 256, 0, stream>>>(qT, kT, vO, aT);
  proj_mfma<<<dim3(64, 4, 4), 256, 0, stream>>>(wp_bf, proj_b, aT, x, out);
}